// Round 11
// baseline (110.203 us; speedup 1.0000x reference)
//
#include <hip/hip_runtime.h>

// Fast HW transcendentals (v_exp_f32 / v_log_f32 / v_rcp_f32), with fallbacks.
#if __has_builtin(__builtin_amdgcn_exp2f)
#define FAST_EXP2(x) __builtin_amdgcn_exp2f(x)
#else
#define FAST_EXP2(x) exp2f(x)
#endif
#if __has_builtin(__builtin_amdgcn_logf)
#define FAST_LOG2(x) __builtin_amdgcn_logf(x)
#else
#define FAST_LOG2(x) log2f(x)
#endif
#if __has_builtin(__builtin_amdgcn_rcpf)
#define FAST_RCP(x) __builtin_amdgcn_rcpf(x)
#else
#define FAST_RCP(x) (1.0f / (x))
#endif

#define LOG2E 1.44269504088896340736f

// Compiler-generated vector math ONLY (rounds 4-6 condemned inline-asm v_pk_*).
typedef float v2f __attribute__((ext_vector_type(2)));

__device__ __forceinline__ v2f v2fma(v2f a, v2f b, v2f c) {
    return __builtin_elementwise_fma(a, b, c);
}

// tanh pair with ganged rcp: 1/a,1/b = t=rcp(a*b); t*b, t*a.
__device__ __forceinline__ v2f fast_tanh2(v2f v) {
    v2f t = v * (v2f)(2.0f * LOG2E);
    v2f e;
    e.x = FAST_EXP2(t.x);
    e.y = FAST_EXP2(t.y);
    v2f d = e + (v2f)(1.0f);
    float tp = FAST_RCP(d.x * d.y);
    v2f r;
    r.x = tp * d.y;
    r.y = tp * d.x;
    return v2fma((v2f)(-2.0f), r, (v2f)(1.0f));
}

// R11 = R10 + ONE change: __launch_bounds__(256, 8).
// Mechanism: R2's direct counters showed OccupancyPercent 48% at VGPR_Count=16
// (granule 8 -> 128 real VGPRs -> 4 waves/SIMD). The R10 body's live set
// (~35 VGPRs) fits in 64, so requesting 8 waves/EU caps the allocator at 64
// VGPRs and doubles wave slots -> fills the trans-latency/LDS-wait issue gaps
// behind the 75-79% VALUBusy.
__global__ __launch_bounds__(256, 8) void subsurf_kernel(
    const float* __restrict__ x, const float* __restrict__ S1,
    const float* __restrict__ W1, const float* __restrict__ b1,
    const float* __restrict__ W2, const float* __restrict__ b2,
    const float* __restrict__ W3, const float* __restrict__ b3,
    float* __restrict__ out, int n)
{
    // Layout: W1[0..72) b1[72..90) W2[90..198) b2[198..216) W3[216..234) b3[234..237)
    __shared__ __align__(16) float w[240];
    int t = threadIdx.x;
    if (t < 72)       w[t] = W1[t];
    else if (t < 90)  w[t] = b1[t - 72];
    else if (t < 198) w[t] = W2[t - 90];
    else if (t < 216) w[t] = b2[t - 198];
    else if (t < 234) w[t] = W3[t - 216];
    else if (t < 237) w[t] = b3[t - 234];
    __syncthreads();

    int i = blockIdx.x * blockDim.x + t;
    if (i >= n) return;

    const v2f* W1p = (const v2f*)(w + 0);    // [(k*4+d)*3 + jp]
    const v2f* b1p = (const v2f*)(w + 72);   // [k*3 + jp]
    const v2f* W2p = (const v2f*)(w + 90);   // [(k*6+ww)*3 + jp]
    const v2f* b2p = (const v2f*)(w + 198);  // [k*3 + jp]
    const float* W3s = w + 216;              // [k*6 + v]
    const float* b3s = w + 234;              // [k]

    // Coalesced 16B/lane load of the 4 features.
    float4 xv = ((const float4*)x)[i];
    float xs[4] = {xv.x, xv.y, xv.z, xv.w};
    float s1 = S1[i];

    // Bit-match numpy f32 constant arithmetic for lows / (highs - lows).
    const float lows[3]   = {100.0f, 0.01f, 0.01f};
    const float ranges[3] = {500.0f - 100.0f, 100.0f - 0.01f, 10.0f - 0.01f};

    float ys[3];
    #pragma unroll
    for (int k = 0; k < 3; ++k) {
        float h1[6];
        #pragma unroll
        for (int jp = 0; jp < 3; ++jp) {
            v2f acc = b1p[k * 3 + jp];
            #pragma unroll
            for (int d = 0; d < 4; ++d)
                acc = v2fma((v2f)(xs[d]), W1p[(k * 4 + d) * 3 + jp], acc);
            v2f th = fast_tanh2(acc);
            h1[2 * jp]     = th.x;
            h1[2 * jp + 1] = th.y;
        }
        float h2[6];
        #pragma unroll
        for (int jp = 0; jp < 3; ++jp) {
            v2f acc = b2p[k * 3 + jp];
            #pragma unroll
            for (int ww = 0; ww < 6; ++ww)
                acc = v2fma((v2f)(h1[ww]), W2p[(k * 6 + ww) * 3 + jp], acc);
            v2f th = fast_tanh2(acc);
            h2[2 * jp]     = th.x;
            h2[2 * jp + 1] = th.y;
        }
        // Layer 3: scalar sequential order.
        float y = b3s[k];
        #pragma unroll
        for (int v = 0; v < 6; ++v)
            y = fmaf(h2[v], W3s[k * 6 + v], y);
        ys[k] = y;
    }

    // Ganged sigmoid trio: s_k = 1/d_k via one rcp of the triple product.
    float d0 = 1.0f + FAST_EXP2(-ys[0] * LOG2E);
    float d1 = 1.0f + FAST_EXP2(-ys[1] * LOG2E);
    float d2 = 1.0f + FAST_EXP2(-ys[2] * LOG2E);
    float p01 = d0 * d1;
    float tp = FAST_RCP(p01 * d2);
    float sg0 = tp * (d1 * d2);
    float sg1 = tp * (d0 * d2);
    float sg2 = tp * p01;

    float S1max = fmaf(ranges[0], sg0, lows[0]);
    float ks    = fmaf(ranges[1], sg1, lows[1]);
    float nexp  = fmaf(ranges[2], sg2, lows[2]);

    // (S1/S1max)^n in log2 domain: handles S1==0 (log2->-inf, exp2->0).
    float lr = FAST_LOG2(s1) - FAST_LOG2(S1max);
    float flow = ks * FAST_EXP2(nexp * lr);
    flow = fminf(fmaxf(flow, 0.0f), S1max);
    out[i] = flow;
}

extern "C" void kernel_launch(void* const* d_in, const int* in_sizes, int n_in,
                              void* d_out, int out_size, void* d_ws, size_t ws_size,
                              hipStream_t stream) {
    const float* x  = (const float*)d_in[0];
    const float* S1 = (const float*)d_in[1];
    const float* W1 = (const float*)d_in[2];
    const float* b1 = (const float*)d_in[3];
    const float* W2 = (const float*)d_in[4];
    const float* b2 = (const float*)d_in[5];
    const float* W3 = (const float*)d_in[6];
    const float* b3 = (const float*)d_in[7];
    float* out = (float*)d_out;

    int n = out_size;  // N = 2,000,000 rows, one output per row
    int block = 256;
    int grid = (n + block - 1) / block;
    subsurf_kernel<<<grid, block, 0, stream>>>(x, S1, W1, b1, W2, b2, W3, b3, out, n);
}